// Round 2
// baseline (107.027 us; speedup 1.0000x reference)
//
#include <hip/hip_runtime.h>

// Problem constants (match reference)
#define NB 32768
#define ND 512
#define NK 10

#define LEFTB (-10.0f)
#define RIGHTB (10.0f)

// ---------------------------------------------------------------------------
// Kernel 1: per-feature spline tables.
// edges : [ND][12]      internal knots cw[1..9] (padded row of 12)
// params: [ND][NK][8]   {cw_k, 1/w_k, ch_k, h_k, delta_k, d_k, d_{k+1}, 0}
// ---------------------------------------------------------------------------
__global__ void rqs_precompute(const float* __restrict__ uw,
                               const float* __restrict__ uh,
                               const float* __restrict__ ud,
                               float* __restrict__ edges,
                               float* __restrict__ params) {
    int f = blockIdx.x * blockDim.x + threadIdx.x;
    if (f >= ND) return;

    float cw[NK + 1], ch[NK + 1], w[NK], h[NK], dd[NK + 1];

    // ---- widths ----
    {
        float u[NK];
        float m = -1e30f;
#pragma unroll
        for (int k = 0; k < NK; ++k) { u[k] = uw[f * NK + k]; m = fmaxf(m, u[k]); }
        float s = 0.0f;
#pragma unroll
        for (int k = 0; k < NK; ++k) { u[k] = expf(u[k] - m); s += u[k]; }
        float inv = 1.0f / s;
        float c = 0.0f;
        cw[0] = LEFTB;
#pragma unroll
        for (int k = 0; k < NK; ++k) {
            float wk = 1e-3f + (1.0f - 1e-3f * NK) * (u[k] * inv);
            c += wk;
            cw[k + 1] = (RIGHTB - LEFTB) * c + LEFTB;
        }
        cw[NK] = RIGHTB;
#pragma unroll
        for (int k = 0; k < NK; ++k) w[k] = cw[k + 1] - cw[k];
    }
    // ---- heights ----
    {
        float u[NK];
        float m = -1e30f;
#pragma unroll
        for (int k = 0; k < NK; ++k) { u[k] = uh[f * NK + k]; m = fmaxf(m, u[k]); }
        float s = 0.0f;
#pragma unroll
        for (int k = 0; k < NK; ++k) { u[k] = expf(u[k] - m); s += u[k]; }
        float inv = 1.0f / s;
        float c = 0.0f;
        ch[0] = LEFTB;
#pragma unroll
        for (int k = 0; k < NK; ++k) {
            float hk = 1e-3f + (1.0f - 1e-3f * NK) * (u[k] * inv);
            c += hk;
            ch[k + 1] = (RIGHTB - LEFTB) * c + LEFTB;
        }
        ch[NK] = RIGHTB;
#pragma unroll
        for (int k = 0; k < NK; ++k) h[k] = ch[k + 1] - ch[k];
    }
    // ---- derivatives: boundary pads are exactly 1.0 ----
    dd[0] = 1.0f;
    dd[NK] = 1.0f;
#pragma unroll
    for (int k = 1; k < NK; ++k) {
        float v = ud[f * (NK - 1) + (k - 1)];
        dd[k] = 1e-3f + (fmaxf(v, 0.0f) + log1pf(expf(-fabsf(v))));
    }

    // ---- store ----
#pragma unroll
    for (int k = 1; k < NK; ++k) edges[f * 12 + (k - 1)] = cw[k];
    edges[f * 12 + 9] = 0.0f; edges[f * 12 + 10] = 0.0f; edges[f * 12 + 11] = 0.0f;
#pragma unroll
    for (int k = 0; k < NK; ++k) {
        float* p = params + ((size_t)(f * NK + k)) * 8;
        p[0] = cw[k];
        p[1] = 1.0f / w[k];
        p[2] = ch[k];
        p[3] = h[k];
        p[4] = h[k] / w[k];   // delta
        p[5] = dd[k];
        p[6] = dd[k + 1];
        p[7] = 0.0f;
    }
}

// ---------------------------------------------------------------------------
// Per-element spline evaluation. e = 9 register edges for this feature,
// P = packed param table base, f = feature index.
// ---------------------------------------------------------------------------
__device__ __forceinline__ void rqs_elem(float x, const float* __restrict__ e,
                                         const float4* __restrict__ P, int f,
                                         float& yo, float& lado) {
    bool inside = (x >= LEFTB) && (x <= RIGHTB);
    float xc = fminf(fmaxf(x, LEFTB), RIGHTB);

    int idx = 0;
#pragma unroll
    for (int j = 0; j < 9; ++j) idx += (xc >= e[j]) ? 1 : 0;

    const float4 a = P[(f * NK + idx) * 2];      // {cw, 1/w, ch, h}
    const float4 b = P[(f * NK + idx) * 2 + 1];  // {delta, dk, dk1, 0}

    float theta = (xc - a.x) * a.y;
    float omt = 1.0f - theta;
    float t1m = theta * omt;
    float th2 = theta * theta;

    float num = a.w * fmaf(b.x, th2, b.y * t1m);
    float den = fmaf(b.y + b.z - 2.0f * b.x, t1m, b.x);
    float rden = __builtin_amdgcn_rcpf(den);     // den > 0 always
    float y = fmaf(num, rden, a.z);

    float dnum = b.x * b.x * (fmaf(b.z, th2, 2.0f * b.x * t1m) + b.y * omt * omt);
    float lad = __logf(dnum * rden * rden);      // log(dnum) - 2 log(den)

    yo = inside ? y : x;
    lado = inside ? lad : 0.0f;
}

// ---------------------------------------------------------------------------
// Kernel 2: main transform. 512 threads; thread t handles features {2g, 2g+1}
// (g = t & 255) of row r0 + (t>>8); 2 rows per block-iteration. float2 x/y.
// ---------------------------------------------------------------------------
__global__ __launch_bounds__(512) void rqs_main(const float* __restrict__ X,
                                                const float* __restrict__ edges,
                                                const float* __restrict__ params,
                                                float* __restrict__ Y,
                                                float* __restrict__ logdet) {
    const int t = threadIdx.x;
    const int rs = t >> 8;       // 0..1: row within the pair
    const int g = t & 255;       // feature pair; features 2g, 2g+1
    const int f0 = 2 * g;
    __shared__ float sred[8];

    float e0[9], e1[9];
#pragma unroll
    for (int j = 0; j < 9; ++j) e0[j] = edges[f0 * 12 + j];
#pragma unroll
    for (int j = 0; j < 9; ++j) e1[j] = edges[(f0 + 1) * 12 + j];

    const float4* P = (const float4*)params;

    for (int r0 = blockIdx.x * 2; r0 < NB; r0 += gridDim.x * 2) {
        const int r = r0 + rs;
        const int base = r * ND + f0;
        const float2 x2 = *(const float2*)(X + base);

        float ya, yb, la, lb;
        rqs_elem(x2.x, e0, P, f0, ya, la);
        rqs_elem(x2.y, e1, P, f0 + 1, yb, lb);

        float2 y2 = make_float2(ya, yb);
        *(float2*)(Y + base) = y2;

        float lad2 = la + lb;
#pragma unroll
        for (int off = 32; off >= 1; off >>= 1) lad2 += __shfl_xor(lad2, off, 64);
        if ((t & 63) == 0) sred[t >> 6] = lad2;
        __syncthreads();
        if (t < 2)
            logdet[r0 + t] = (sred[4 * t] + sred[4 * t + 1]) +
                             (sred[4 * t + 2] + sred[4 * t + 3]);
        __syncthreads();
    }
}

extern "C" void kernel_launch(void* const* d_in, const int* in_sizes, int n_in,
                              void* d_out, int out_size, void* d_ws, size_t ws_size,
                              hipStream_t stream) {
    const float* x  = (const float*)d_in[0];
    const float* uw = (const float*)d_in[1];
    const float* uh = (const float*)d_in[2];
    const float* ud = (const float*)d_in[3];

    float* out = (float*)d_out;
    float* Y = out;                              // [NB*ND]
    float* logdet = out + (size_t)NB * ND;       // [NB]

    float* edges = (float*)d_ws;                 // ND*12 floats  (24 KB)
    float* params = edges + ND * 12;             // ND*NK*8 floats (160 KB)

    hipLaunchKernelGGL(rqs_precompute, dim3(2), dim3(256), 0, stream,
                       uw, uh, ud, edges, params);
    hipLaunchKernelGGL(rqs_main, dim3(2048), dim3(512), 0, stream,
                       x, edges, params, Y, logdet);
}

// Round 3
// 80.383 us; speedup vs baseline: 1.3315x; 1.3315x over previous
//
#include <hip/hip_runtime.h>

// Problem constants (match reference)
#define NB 32768
#define ND 512
#define NK 10

#define LEFTB (-10.0f)
#define RIGHTB (10.0f)
#define ROWS 4

// ---------------------------------------------------------------------------
// Kernel 1: per-feature spline tables.
// edges : [ND][12]      internal knots cw[1..9] (padded row of 12)
// params: [ND][NK][8]   {cw_k, 1/w_k, ch_k, h_k, delta_k, d_k, d_{k+1}, 0}
// ---------------------------------------------------------------------------
__global__ void rqs_precompute(const float* __restrict__ uw,
                               const float* __restrict__ uh,
                               const float* __restrict__ ud,
                               float* __restrict__ edges,
                               float* __restrict__ params) {
    int f = blockIdx.x * blockDim.x + threadIdx.x;
    if (f >= ND) return;

    float cw[NK + 1], ch[NK + 1], w[NK], h[NK], dd[NK + 1];

    // ---- widths ----
    {
        float u[NK];
        float m = -1e30f;
#pragma unroll
        for (int k = 0; k < NK; ++k) { u[k] = uw[f * NK + k]; m = fmaxf(m, u[k]); }
        float s = 0.0f;
#pragma unroll
        for (int k = 0; k < NK; ++k) { u[k] = expf(u[k] - m); s += u[k]; }
        float inv = 1.0f / s;
        float c = 0.0f;
        cw[0] = LEFTB;
#pragma unroll
        for (int k = 0; k < NK; ++k) {
            float wk = 1e-3f + (1.0f - 1e-3f * NK) * (u[k] * inv);
            c += wk;
            cw[k + 1] = (RIGHTB - LEFTB) * c + LEFTB;
        }
        cw[NK] = RIGHTB;
#pragma unroll
        for (int k = 0; k < NK; ++k) w[k] = cw[k + 1] - cw[k];
    }
    // ---- heights ----
    {
        float u[NK];
        float m = -1e30f;
#pragma unroll
        for (int k = 0; k < NK; ++k) { u[k] = uh[f * NK + k]; m = fmaxf(m, u[k]); }
        float s = 0.0f;
#pragma unroll
        for (int k = 0; k < NK; ++k) { u[k] = expf(u[k] - m); s += u[k]; }
        float inv = 1.0f / s;
        float c = 0.0f;
        ch[0] = LEFTB;
#pragma unroll
        for (int k = 0; k < NK; ++k) {
            float hk = 1e-3f + (1.0f - 1e-3f * NK) * (u[k] * inv);
            c += hk;
            ch[k + 1] = (RIGHTB - LEFTB) * c + LEFTB;
        }
        ch[NK] = RIGHTB;
#pragma unroll
        for (int k = 0; k < NK; ++k) h[k] = ch[k + 1] - ch[k];
    }
    // ---- derivatives: boundary pads are exactly 1.0 ----
    dd[0] = 1.0f;
    dd[NK] = 1.0f;
#pragma unroll
    for (int k = 1; k < NK; ++k) {
        float v = ud[f * (NK - 1) + (k - 1)];
        dd[k] = 1e-3f + (fmaxf(v, 0.0f) + log1pf(expf(-fabsf(v))));
    }

    // ---- store ----
#pragma unroll
    for (int k = 1; k < NK; ++k) edges[f * 12 + (k - 1)] = cw[k];
    edges[f * 12 + 9] = 0.0f; edges[f * 12 + 10] = 0.0f; edges[f * 12 + 11] = 0.0f;
#pragma unroll
    for (int k = 0; k < NK; ++k) {
        float* p = params + ((size_t)(f * NK + k)) * 8;
        p[0] = cw[k];
        p[1] = 1.0f / w[k];
        p[2] = ch[k];
        p[3] = h[k];
        p[4] = h[k] / w[k];   // delta
        p[5] = dd[k];
        p[6] = dd[k + 1];
        p[7] = 0.0f;
    }
}

// ---------------------------------------------------------------------------
// Per-element spline evaluation. e = 9 register edges, Pt = this feature's
// packed param rows (NK bins x 2 float4).
// ---------------------------------------------------------------------------
__device__ __forceinline__ void rqs_elem(float x, const float* __restrict__ e,
                                         const float4* __restrict__ Pt,
                                         float& yo, float& lado) {
    bool inside = (x >= LEFTB) && (x <= RIGHTB);
    float xc = fminf(fmaxf(x, LEFTB), RIGHTB);

    int idx = 0;
#pragma unroll
    for (int j = 0; j < 9; ++j) idx += (xc >= e[j]) ? 1 : 0;

    const float4 a = Pt[idx * 2];      // {cw, 1/w, ch, h}
    const float4 b = Pt[idx * 2 + 1];  // {delta, dk, dk1, 0}

    float theta = (xc - a.x) * a.y;
    float omt = 1.0f - theta;
    float t1m = theta * omt;
    float th2 = theta * theta;

    float num = a.w * fmaf(b.x, th2, b.y * t1m);
    float den = fmaf(b.y + b.z - 2.0f * b.x, t1m, b.x);
    float rden = __builtin_amdgcn_rcpf(den);     // den > 0 always
    float y = fmaf(num, rden, a.z);

    float dnum = b.x * b.x * (fmaf(b.z, th2, 2.0f * b.x * t1m) + b.y * omt * omt);
    float lad = __logf(dnum * rden * rden);      // log(dnum) - 2 log(den)

    yo = inside ? y : x;
    lado = inside ? lad : 0.0f;
}

// ---------------------------------------------------------------------------
// Kernel 2a: main transform. Thread t = feature t (fixed -> 20 KB param slice
// per wave stays L1-resident). ROWS rows per iteration for MLP. No barriers,
// no LDS: 4-level DPP shuffle reduce -> 32 partials per row into d_ws.
// ---------------------------------------------------------------------------
__global__ __launch_bounds__(512) void rqs_main(const float* __restrict__ X,
                                                const float* __restrict__ edges,
                                                const float* __restrict__ params,
                                                float* __restrict__ Y,
                                                float* __restrict__ part) {
    const int t = threadIdx.x;  // feature index

    float e[9];
#pragma unroll
    for (int j = 0; j < 9; ++j) e[j] = edges[t * 12 + j];

    const float4* Pt = ((const float4*)params) + t * (NK * 2);

    for (int r0 = blockIdx.x * ROWS; r0 < NB; r0 += gridDim.x * ROWS) {
        float xs[ROWS], ys[ROWS], ls[ROWS];
#pragma unroll
        for (int i = 0; i < ROWS; ++i) xs[i] = X[(r0 + i) * ND + t];
#pragma unroll
        for (int i = 0; i < ROWS; ++i) rqs_elem(xs[i], e, Pt, ys[i], ls[i]);
#pragma unroll
        for (int i = 0; i < ROWS; ++i)
            __builtin_nontemporal_store(ys[i], &Y[(r0 + i) * ND + t]);

        // 4-level xor reduce (offsets 1,2,4,8 lower to DPP row ops)
#pragma unroll
        for (int off = 1; off <= 8; off <<= 1) {
#pragma unroll
            for (int i = 0; i < ROWS; ++i) ls[i] += __shfl_xor(ls[i], off, 64);
        }
        if ((t & 15) == 0) {
            int g = t >> 4;  // 0..31
#pragma unroll
            for (int i = 0; i < ROWS; ++i) part[(r0 + i) * 32 + g] = ls[i];
        }
    }
}

// ---------------------------------------------------------------------------
// Kernel 2b: logdet = sum of 32 partials per row. 8 threads per row, float4.
// ---------------------------------------------------------------------------
__global__ __launch_bounds__(256) void rqs_reduce(const float* __restrict__ part,
                                                  float* __restrict__ logdet) {
    int j = blockIdx.x * 256 + threadIdx.x;
    int row = j >> 3;
    int sub = j & 7;
    float4 v = ((const float4*)part)[row * 8 + sub];
    float s = (v.x + v.y) + (v.z + v.w);
    s += __shfl_xor(s, 1, 64);
    s += __shfl_xor(s, 2, 64);
    s += __shfl_xor(s, 4, 64);
    if (sub == 0) logdet[row] = s;
}

// ---------------------------------------------------------------------------
// Fallback main kernel (round-1 proven path, needs only 188 KB ws): used if
// ws_size can't hold the 4 MB partial buffer.
// ---------------------------------------------------------------------------
__global__ __launch_bounds__(512) void rqs_main_fb(const float* __restrict__ X,
                                                   const float* __restrict__ edges,
                                                   const float* __restrict__ params,
                                                   float* __restrict__ Y,
                                                   float* __restrict__ logdet) {
    const int t = threadIdx.x;
    __shared__ float sred[8];

    float e[9];
#pragma unroll
    for (int j = 0; j < 9; ++j) e[j] = edges[t * 12 + j];
    const float4* Pt = ((const float4*)params) + t * (NK * 2);

    for (int r = blockIdx.x; r < NB; r += gridDim.x) {
        const int base = r * ND + t;
        float y, lad;
        rqs_elem(X[base], e, Pt, y, lad);
        Y[base] = y;

        float v = lad;
#pragma unroll
        for (int off = 32; off >= 1; off >>= 1) v += __shfl_xor(v, off, 64);
        if ((t & 63) == 0) sred[t >> 6] = v;
        __syncthreads();
        if (t == 0) {
            float s = 0.0f;
#pragma unroll
            for (int k = 0; k < 8; ++k) s += sred[k];
            logdet[r] = s;
        }
        __syncthreads();
    }
}

extern "C" void kernel_launch(void* const* d_in, const int* in_sizes, int n_in,
                              void* d_out, int out_size, void* d_ws, size_t ws_size,
                              hipStream_t stream) {
    const float* x  = (const float*)d_in[0];
    const float* uw = (const float*)d_in[1];
    const float* uh = (const float*)d_in[2];
    const float* ud = (const float*)d_in[3];

    float* out = (float*)d_out;
    float* Y = out;                              // [NB*ND]
    float* logdet = out + (size_t)NB * ND;       // [NB]

    float* edges = (float*)d_ws;                 // ND*12 floats  (24 KB)
    float* params = edges + ND * 12;             // ND*NK*8 floats (160 KB)
    float* part = params + ND * NK * 8;          // NB*32 floats  (4 MB)

    const size_t needed = (size_t)(ND * 12 + ND * NK * 8 + NB * 32) * 4;

    hipLaunchKernelGGL(rqs_precompute, dim3(2), dim3(256), 0, stream,
                       uw, uh, ud, edges, params);

    if (ws_size >= needed) {
        hipLaunchKernelGGL(rqs_main, dim3(1024), dim3(512), 0, stream,
                           x, edges, params, Y, part);
        hipLaunchKernelGGL(rqs_reduce, dim3(NB * 8 / 256), dim3(256), 0, stream,
                           part, logdet);
    } else {
        hipLaunchKernelGGL(rqs_main_fb, dim3(2048), dim3(512), 0, stream,
                           x, edges, params, Y, logdet);
    }
}

// Round 4
// 59.358 us; speedup vs baseline: 1.8031x; 1.3542x over previous
//
#include <hip/hip_runtime.h>

// Problem constants (match reference)
#define NB 32768
#define ND 512
#define NK 10

#define LEFTB (-10.0f)
#define RIGHTB (10.0f)
#define ROWS 4

// ---------------------------------------------------------------------------
// Workspace layout (all SoA, [param][feature] for coalesced per-thread loads):
//   E  [ 9][ND]  internal knots cw[1..9]
//   RW [10][ND]  1/w_k
//   CH [10][ND]  ch_k (left y-knot of bin k)
//   H  [10][ND]  h_k
//   DD [11][ND]  d_k (derivatives at knots)
//   part [NB][32] per-row partial sums for logdet
// ---------------------------------------------------------------------------

__global__ void rqs_precompute(const float* __restrict__ uw,
                               const float* __restrict__ uh,
                               const float* __restrict__ ud,
                               float* __restrict__ ws) {
    int f = blockIdx.x * blockDim.x + threadIdx.x;
    if (f >= ND) return;

    float* E  = ws;
    float* RW = E + 9 * ND;
    float* CH = RW + 10 * ND;
    float* H  = CH + 10 * ND;
    float* DD = H + 10 * ND;

    float cw[NK + 1], ch[NK + 1], w[NK], h[NK], dd[NK + 1];

    // ---- widths ----
    {
        float u[NK];
        float m = -1e30f;
#pragma unroll
        for (int k = 0; k < NK; ++k) { u[k] = uw[f * NK + k]; m = fmaxf(m, u[k]); }
        float s = 0.0f;
#pragma unroll
        for (int k = 0; k < NK; ++k) { u[k] = expf(u[k] - m); s += u[k]; }
        float inv = 1.0f / s;
        float c = 0.0f;
        cw[0] = LEFTB;
#pragma unroll
        for (int k = 0; k < NK; ++k) {
            float wk = 1e-3f + (1.0f - 1e-3f * NK) * (u[k] * inv);
            c += wk;
            cw[k + 1] = (RIGHTB - LEFTB) * c + LEFTB;
        }
        cw[NK] = RIGHTB;
#pragma unroll
        for (int k = 0; k < NK; ++k) w[k] = cw[k + 1] - cw[k];
    }
    // ---- heights ----
    {
        float u[NK];
        float m = -1e30f;
#pragma unroll
        for (int k = 0; k < NK; ++k) { u[k] = uh[f * NK + k]; m = fmaxf(m, u[k]); }
        float s = 0.0f;
#pragma unroll
        for (int k = 0; k < NK; ++k) { u[k] = expf(u[k] - m); s += u[k]; }
        float inv = 1.0f / s;
        float c = 0.0f;
        ch[0] = LEFTB;
#pragma unroll
        for (int k = 0; k < NK; ++k) {
            float hk = 1e-3f + (1.0f - 1e-3f * NK) * (u[k] * inv);
            c += hk;
            ch[k + 1] = (RIGHTB - LEFTB) * c + LEFTB;
        }
        ch[NK] = RIGHTB;
#pragma unroll
        for (int k = 0; k < NK; ++k) h[k] = ch[k + 1] - ch[k];
    }
    // ---- derivatives: boundary pads are exactly 1.0 ----
    dd[0] = 1.0f;
    dd[NK] = 1.0f;
#pragma unroll
    for (int k = 1; k < NK; ++k) {
        float v = ud[f * (NK - 1) + (k - 1)];
        dd[k] = 1e-3f + (fmaxf(v, 0.0f) + log1pf(expf(-fabsf(v))));
    }

    // ---- store SoA ----
#pragma unroll
    for (int j = 0; j < 9; ++j) E[j * ND + f] = cw[j + 1];
#pragma unroll
    for (int k = 0; k < NK; ++k) {
        RW[k * ND + f] = 1.0f / w[k];
        CH[k * ND + f] = ch[k];
        H[k * ND + f] = h[k];
    }
#pragma unroll
    for (int k = 0; k <= NK; ++k) DD[k * ND + f] = dd[k];
}

// ---------------------------------------------------------------------------
// Main transform. Thread t = feature t. ALL spline params for the feature
// live in registers (50 floats); bin selection is a 9-step cndmask chain —
// zero per-element memory traffic beyond coalesced x load / y store.
// ---------------------------------------------------------------------------
__global__ __launch_bounds__(512, 4) void rqs_main(const float* __restrict__ X,
                                                   const float* __restrict__ ws,
                                                   float* __restrict__ Y,
                                                   float* __restrict__ part) {
    const int t = threadIdx.x;  // feature index

    const float* E  = ws;
    const float* RW = E + 9 * ND;
    const float* CH = RW + 10 * ND;
    const float* H  = CH + 10 * ND;
    const float* DD = H + 10 * ND;

    float e[9], rw[NK], chv[NK], hv[NK], dd[NK + 1];
#pragma unroll
    for (int j = 0; j < 9; ++j) e[j] = E[j * ND + t];
#pragma unroll
    for (int k = 0; k < NK; ++k) {
        rw[k] = RW[k * ND + t];
        chv[k] = CH[k * ND + t];
        hv[k] = H[k * ND + t];
    }
#pragma unroll
    for (int k = 0; k <= NK; ++k) dd[k] = DD[k * ND + t];

    for (int r0 = blockIdx.x * ROWS; r0 < NB; r0 += gridDim.x * ROWS) {
        float xs[ROWS], ys[ROWS], ls[ROWS];
#pragma unroll
        for (int i = 0; i < ROWS; ++i) xs[i] = X[(r0 + i) * ND + t];

#pragma unroll
        for (int i = 0; i < ROWS; ++i) {
            float x = xs[i];
            bool inside = (x >= LEFTB) && (x <= RIGHTB);
            float xc = fminf(fmaxf(x, LEFTB), RIGHTB);

            // 9-step predicated select of the active bin's params
            float cwS = LEFTB, rwS = rw[0], chS = chv[0], hS = hv[0];
            float dkS = dd[0], dk1S = dd[1];
#pragma unroll
            for (int j = 0; j < 9; ++j) {
                bool c = (xc >= e[j]);
                cwS  = c ? e[j]      : cwS;
                rwS  = c ? rw[j + 1] : rwS;
                chS  = c ? chv[j + 1] : chS;
                hS   = c ? hv[j + 1] : hS;
                dkS  = c ? dd[j + 1] : dkS;
                dk1S = c ? dd[j + 2] : dk1S;
            }
            float delta = hS * rwS;

            float theta = (xc - cwS) * rwS;
            float omt = 1.0f - theta;
            float t1m = theta * omt;
            float th2 = theta * theta;

            float num = hS * fmaf(delta, th2, dkS * t1m);
            float den = fmaf(dkS + dk1S - 2.0f * delta, t1m, delta);
            float rden = __builtin_amdgcn_rcpf(den);  // den > 0 always
            float y = fmaf(num, rden, chS);

            float dnum = delta * delta *
                         (fmaf(dk1S, th2, 2.0f * delta * t1m) + dkS * omt * omt);
            float lad = __logf(dnum * rden * rden);  // log(dnum) - 2 log(den)

            ys[i] = inside ? y : x;
            ls[i] = inside ? lad : 0.0f;
        }

#pragma unroll
        for (int i = 0; i < ROWS; ++i)
            __builtin_nontemporal_store(ys[i], &Y[(r0 + i) * ND + t]);

        // 4-level xor reduce (DPP row ops) -> 32 partials per row
#pragma unroll
        for (int off = 1; off <= 8; off <<= 1) {
#pragma unroll
            for (int i = 0; i < ROWS; ++i) ls[i] += __shfl_xor(ls[i], off, 64);
        }
        if ((t & 15) == 0) {
            int g = t >> 4;  // 0..31
#pragma unroll
            for (int i = 0; i < ROWS; ++i) part[(r0 + i) * 32 + g] = ls[i];
        }
    }
}

// ---------------------------------------------------------------------------
// logdet = sum of 32 partials per row. 8 threads per row, float4.
// ---------------------------------------------------------------------------
__global__ __launch_bounds__(256) void rqs_reduce(const float* __restrict__ part,
                                                  float* __restrict__ logdet) {
    int j = blockIdx.x * 256 + threadIdx.x;
    int row = j >> 3;
    int sub = j & 7;
    float4 v = ((const float4*)part)[row * 8 + sub];
    float s = (v.x + v.y) + (v.z + v.w);
    s += __shfl_xor(s, 1, 64);
    s += __shfl_xor(s, 2, 64);
    s += __shfl_xor(s, 4, 64);
    if (sub == 0) logdet[row] = s;
}

extern "C" void kernel_launch(void* const* d_in, const int* in_sizes, int n_in,
                              void* d_out, int out_size, void* d_ws, size_t ws_size,
                              hipStream_t stream) {
    const float* x  = (const float*)d_in[0];
    const float* uw = (const float*)d_in[1];
    const float* uh = (const float*)d_in[2];
    const float* ud = (const float*)d_in[3];

    float* out = (float*)d_out;
    float* Y = out;                              // [NB*ND]
    float* logdet = out + (size_t)NB * ND;       // [NB]

    float* ws = (float*)d_ws;                    // 50*ND floats (100 KB)
    float* part = ws + 50 * ND;                  // NB*32 floats (4 MB)

    hipLaunchKernelGGL(rqs_precompute, dim3(2), dim3(256), 0, stream,
                       uw, uh, ud, ws);
    hipLaunchKernelGGL(rqs_main, dim3(1024), dim3(512), 0, stream,
                       x, ws, Y, part);
    hipLaunchKernelGGL(rqs_reduce, dim3(NB * 8 / 256), dim3(256), 0, stream,
                       part, logdet);
}

// Round 5
// 48.929 us; speedup vs baseline: 2.1874x; 1.2131x over previous
//
#include <hip/hip_runtime.h>

// Problem constants (match reference)
#define NB 32768
#define ND 512
#define NK 10

#define LEFTB (-10.0f)
#define RIGHTB (10.0f)
#define ROWS 4
#define BX 1024  // x-blocks; grid = (BX, 2), block = 256 threads

// ---------------------------------------------------------------------------
// Workspace layout (floats):
//   E     [ 9][512]          internal knots cw[1..9] (for register compares)
//   GCWCH [11][512] float2   {cw_k, ch_k} knot pairs
//   GDD   [11][512]          d_k
//   part  [NB][32]           per-row partial sums for logdet
// ---------------------------------------------------------------------------

__global__ void rqs_precompute(const float* __restrict__ uw,
                               const float* __restrict__ uh,
                               const float* __restrict__ ud,
                               float* __restrict__ ws) {
    int f = blockIdx.x * blockDim.x + threadIdx.x;
    if (f >= ND) return;

    float* E = ws;                                // 9*512
    float2* GCWCH = (float2*)(ws + 9 * ND);       // 11*512 float2
    float* GDD = ws + 9 * ND + 22 * ND;           // 11*512

    float cw[NK + 1], ch[NK + 1], dd[NK + 1];

    // ---- widths -> x-knots ----
    {
        float u[NK];
        float m = -1e30f;
#pragma unroll
        for (int k = 0; k < NK; ++k) { u[k] = uw[f * NK + k]; m = fmaxf(m, u[k]); }
        float s = 0.0f;
#pragma unroll
        for (int k = 0; k < NK; ++k) { u[k] = expf(u[k] - m); s += u[k]; }
        float inv = 1.0f / s;
        float c = 0.0f;
        cw[0] = LEFTB;
#pragma unroll
        for (int k = 0; k < NK; ++k) {
            float wk = 1e-3f + (1.0f - 1e-3f * NK) * (u[k] * inv);
            c += wk;
            cw[k + 1] = (RIGHTB - LEFTB) * c + LEFTB;
        }
        cw[NK] = RIGHTB;
    }
    // ---- heights -> y-knots ----
    {
        float u[NK];
        float m = -1e30f;
#pragma unroll
        for (int k = 0; k < NK; ++k) { u[k] = uh[f * NK + k]; m = fmaxf(m, u[k]); }
        float s = 0.0f;
#pragma unroll
        for (int k = 0; k < NK; ++k) { u[k] = expf(u[k] - m); s += u[k]; }
        float inv = 1.0f / s;
        float c = 0.0f;
        ch[0] = LEFTB;
#pragma unroll
        for (int k = 0; k < NK; ++k) {
            float hk = 1e-3f + (1.0f - 1e-3f * NK) * (u[k] * inv);
            c += hk;
            ch[k + 1] = (RIGHTB - LEFTB) * c + LEFTB;
        }
        ch[NK] = RIGHTB;
    }
    // ---- derivatives: boundary pads are exactly 1.0 ----
    dd[0] = 1.0f;
    dd[NK] = 1.0f;
#pragma unroll
    for (int k = 1; k < NK; ++k) {
        float v = ud[f * (NK - 1) + (k - 1)];
        dd[k] = 1e-3f + (fmaxf(v, 0.0f) + log1pf(expf(-fabsf(v))));
    }

    // ---- store ----
#pragma unroll
    for (int j = 0; j < 9; ++j) E[j * ND + f] = cw[j + 1];
#pragma unroll
    for (int k = 0; k <= NK; ++k) {
        GCWCH[k * ND + f] = make_float2(cw[k], ch[k]);
        GDD[k * ND + f] = dd[k];
    }
}

// ---------------------------------------------------------------------------
// Main transform. Block = 256 threads = 256 features (half selected by
// blockIdx.y). Knot tables staged in LDS with SoA [knot][feature] layout:
// plane stride 256 dwords (==0 mod 32 banks) -> per-lane idx gather is
// bank-conflict-free. Edges for the bin search stay in registers.
// ---------------------------------------------------------------------------
__global__ __launch_bounds__(256) void rqs_main(const float* __restrict__ X,
                                                const float* __restrict__ ws,
                                                float* __restrict__ Y,
                                                float* __restrict__ part) {
    const int t = threadIdx.x;
    const int half = blockIdx.y;
    const int f = half * 256 + t;

    const float* E = ws;
    const float2* GCWCH = (const float2*)(ws + 9 * ND);
    const float* GDD = ws + 9 * ND + 22 * ND;

    __shared__ float2 sCWCH[NK + 1][256];  // 22528 B
    __shared__ float sDD[NK + 1][256];     // 11264 B

#pragma unroll
    for (int k = 0; k <= NK; ++k) {
        sCWCH[k][t] = GCWCH[k * ND + f];
        sDD[k][t] = GDD[k * ND + f];
    }
    float e[9];
#pragma unroll
    for (int j = 0; j < 9; ++j) e[j] = E[j * ND + f];
    __syncthreads();

    for (int r0 = blockIdx.x * ROWS; r0 < NB; r0 += gridDim.x * ROWS) {
        float xs[ROWS], ys[ROWS], ls[ROWS];
#pragma unroll
        for (int i = 0; i < ROWS; ++i) xs[i] = X[(r0 + i) * ND + f];

#pragma unroll
        for (int i = 0; i < ROWS; ++i) {
            float x = xs[i];
            bool inside = (x >= LEFTB) && (x <= RIGHTB);
            float xc = fminf(fmaxf(x, LEFTB), RIGHTB);

            int idx = 0;
#pragma unroll
            for (int j = 0; j < 9; ++j) idx += (xc >= e[j]) ? 1 : 0;

            float2 c0 = sCWCH[idx][t];      // {cw_k,   ch_k}
            float2 c1 = sCWCH[idx + 1][t];  // {cw_k+1, ch_k+1}
            float dk = sDD[idx][t];
            float dk1 = sDD[idx + 1][t];

            float w = c1.x - c0.x;
            float rw = __builtin_amdgcn_rcpf(w);   // w >= 0.02 always
            float h = c1.y - c0.y;
            float delta = h * rw;

            float theta = (xc - c0.x) * rw;
            float omt = 1.0f - theta;
            float t1m = theta * omt;
            float th2 = theta * theta;

            float num = h * fmaf(delta, th2, dk * t1m);
            float den = fmaf(dk + dk1 - 2.0f * delta, t1m, delta);
            float rden = __builtin_amdgcn_rcpf(den);  // den > 0 always
            float y = fmaf(num, rden, c0.y);

            float dnum = delta * delta *
                         (fmaf(dk1, th2, 2.0f * delta * t1m) + dk * omt * omt);
            float lad = __logf(dnum * rden * rden);  // log(dnum) - 2 log(den)

            ys[i] = inside ? y : x;
            ls[i] = inside ? lad : 0.0f;
        }

#pragma unroll
        for (int i = 0; i < ROWS; ++i)
            __builtin_nontemporal_store(ys[i], &Y[(r0 + i) * ND + f]);

        // 4-level xor reduce (DPP row ops) -> 16 partials per row-half
#pragma unroll
        for (int off = 1; off <= 8; off <<= 1) {
#pragma unroll
            for (int i = 0; i < ROWS; ++i) ls[i] += __shfl_xor(ls[i], off, 64);
        }
        if ((t & 15) == 0) {
            int g = half * 16 + (t >> 4);  // 0..31 across both halves
#pragma unroll
            for (int i = 0; i < ROWS; ++i) part[(r0 + i) * 32 + g] = ls[i];
        }
    }
}

// ---------------------------------------------------------------------------
// logdet = sum of 32 partials per row. 8 threads per row, float4.
// ---------------------------------------------------------------------------
__global__ __launch_bounds__(256) void rqs_reduce(const float* __restrict__ part,
                                                  float* __restrict__ logdet) {
    int j = blockIdx.x * 256 + threadIdx.x;
    int row = j >> 3;
    int sub = j & 7;
    float4 v = ((const float4*)part)[row * 8 + sub];
    float s = (v.x + v.y) + (v.z + v.w);
    s += __shfl_xor(s, 1, 64);
    s += __shfl_xor(s, 2, 64);
    s += __shfl_xor(s, 4, 64);
    if (sub == 0) logdet[row] = s;
}

extern "C" void kernel_launch(void* const* d_in, const int* in_sizes, int n_in,
                              void* d_out, int out_size, void* d_ws, size_t ws_size,
                              hipStream_t stream) {
    const float* x  = (const float*)d_in[0];
    const float* uw = (const float*)d_in[1];
    const float* uh = (const float*)d_in[2];
    const float* ud = (const float*)d_in[3];

    float* out = (float*)d_out;
    float* Y = out;                              // [NB*ND]
    float* logdet = out + (size_t)NB * ND;       // [NB]

    float* ws = (float*)d_ws;                    // tables: (9+22+11)*512 floats (84 KB)
    float* part = ws + (9 + 22 + 11) * ND;       // NB*32 floats (4 MB)

    hipLaunchKernelGGL(rqs_precompute, dim3(2), dim3(256), 0, stream,
                       uw, uh, ud, ws);
    hipLaunchKernelGGL(rqs_main, dim3(BX, 2), dim3(256), 0, stream,
                       x, ws, Y, part);
    hipLaunchKernelGGL(rqs_reduce, dim3(NB * 8 / 256), dim3(256), 0, stream,
                       part, logdet);
}